// Round 3
// baseline (354.270 us; speedup 1.0000x reference)
//
#include <hip/hip_runtime.h>

#define Bsz 4096
#define Tlen 512
#define IND 18
#define HD 12

__device__ __forceinline__ float sigmoid_f(float x) {
  return __builtin_amdgcn_rcpf(1.0f + __expf(-x));
}
__device__ __forceinline__ float tanh_f(float x) {
  // tanh(x) = 1 - 2/(1+exp(2x)); saturates correctly at +-inf
  return 1.0f - 2.0f * __builtin_amdgcn_rcpf(1.0f + __expf(2.0f * x));
}
// Sum over lane pairs (l, l^32): v_permlane32_swap (pure VALU, no LDS/lgkmcnt).
// For outputs (r0, r1) of swap(v, v), r0[l] + r1[l] == v[l] + v[l^32] under
// either interleave convention.
__device__ __forceinline__ float xor32_sum(float v) {
  unsigned int u = __float_as_uint(v);
  auto r = __builtin_amdgcn_permlane32_swap(u, u, false, false);
  return __uint_as_float(r[0]) + __uint_as_float(r[1]);
}

// 32 lanes per batch element: j = tid&15 (12 active), batch-bit = bit4,
// k-half = bit5 (so reduction partner is lane^32 -> permlane32_swap).
// 4096 batches * 32 lanes = 2048 waves = 2 waves/SIMD.
// LDS only for the h1/h2 broadcasts (write early, read late); FC of step t
// is deferred into step t+1 so no LDS read fences right after its write.
extern "C" __global__ void __launch_bounds__(256, 2) gru2_pl32(
    const float* __restrict__ x,
    const float* __restrict__ wih0, const float* __restrict__ whh0,
    const float* __restrict__ bih0, const float* __restrict__ bhh0,
    const float* __restrict__ wih1, const float* __restrict__ whh1,
    const float* __restrict__ bih1, const float* __restrict__ bhh1,
    const float* __restrict__ fcw, const float* __restrict__ fcb,
    float* __restrict__ out)
{
  const int tid    = threadIdx.x;
  const int lane15 = tid & 15;                 // gate/h index j
  const int hl     = (tid >> 5) & 1;           // k-half (partner = lane^32)
  const int g      = ((tid >> 6) << 1) | ((tid >> 4) & 1);  // batch within block (0..7)
  const int b      = blockIdx.x * 8 + g;
  const int j      = (lane15 < HD) ? lane15 : (HD - 1);
  const bool act   = (lane15 < HD);

  // per-batch LDS: [0..11]=h1, [20..31]=h2; stride 40 floats
  __shared__ float lds[8][40];
  float* sh1 = &lds[g][0];
  float* sh2 = &lds[g][20];

  // ---- per-lane weight slices (k-split by hl) ----
  float wrx[9], wzx[9], wnx[9];          // layer0 ih, rows j / 12+j / 24+j, k = hl*9+i
#pragma unroll
  for (int i = 0; i < 9; ++i) {
    wrx[i] = wih0[(0 * HD + j) * IND + hl * 9 + i];
    wzx[i] = wih0[(1 * HD + j) * IND + hl * 9 + i];
    wnx[i] = wih0[(2 * HD + j) * IND + hl * 9 + i];
  }
  float wrh[6], wzh[6], wnh[6];          // layer0 hh, k = hl*6+i
  float wr1i[6], wz1i[6], wn1i[6];       // layer1 ih
  float wr1h[6], wz1h[6], wn1h[6];       // layer1 hh
  float fw6[6];
#pragma unroll
  for (int i = 0; i < 6; ++i) {
    int k = hl * 6 + i;
    wrh[i]  = whh0[(0 * HD + j) * HD + k];
    wzh[i]  = whh0[(1 * HD + j) * HD + k];
    wnh[i]  = whh0[(2 * HD + j) * HD + k];
    wr1i[i] = wih1[(0 * HD + j) * HD + k];
    wz1i[i] = wih1[(1 * HD + j) * HD + k];
    wn1i[i] = wih1[(2 * HD + j) * HD + k];
    wr1h[i] = whh1[(0 * HD + j) * HD + k];
    wz1h[i] = whh1[(1 * HD + j) * HD + k];
    wn1h[i] = whh1[(2 * HD + j) * HD + k];
    fw6[i]  = fcw[k];
  }
  // biases folded into half-0 partials only
  const float rb0  = hl ? 0.f : (bih0[j] + bhh0[j]);
  const float zb0  = hl ? 0.f : (bih0[HD + j] + bhh0[HD + j]);
  const float inb0 = hl ? 0.f : bih0[2 * HD + j];
  const float hnb0 = hl ? 0.f : bhh0[2 * HD + j];
  const float rb1  = hl ? 0.f : (bih1[j] + bhh1[j]);
  const float zb1  = hl ? 0.f : (bih1[HD + j] + bhh1[HD + j]);
  const float inb1 = hl ? 0.f : bih1[2 * HD + j];
  const float hnb1 = hl ? 0.f : bhh1[2 * HD + j];
  const float fb_l = hl ? 0.f : fcb[0];

  // ---- state ----
  float hv1h[6], hv2h[6];                // my k-half of h1_{t-1}, h2_{t-1}
#pragma unroll
  for (int i = 0; i < 6; ++i) { hv1h[i] = 0.f; hv2h[i] = 0.f; }
  float h1 = 0.f, h2 = 0.f;

  const float* xp = x + (size_t)b * Tlen * IND + hl * 9;  // my 9 floats per step
  float* outp = out + (size_t)b * Tlen;

  float xA[9], xB[9];
#pragma unroll
  for (int i = 0; i < 9; ++i) xA[i] = xp[i];

#define STEP(XV, TT)                                                                    \
  do {                                                                                  \
    /* ---- layer 0 partial dots (x half + h1 half) ---- */                             \
    float rp = rb0, zp = zb0, inp = inb0, hnp = hnb0;                                   \
    _Pragma("unroll")                                                                   \
    for (int i = 0; i < 9; ++i) {                                                       \
      rp += XV[i] * wrx[i]; zp += XV[i] * wzx[i]; inp += XV[i] * wnx[i];                \
    }                                                                                   \
    _Pragma("unroll")                                                                   \
    for (int i = 0; i < 6; ++i) {                                                       \
      rp += hv1h[i] * wrh[i]; zp += hv1h[i] * wzh[i]; hnp += hv1h[i] * wnh[i];          \
    }                                                                                   \
    float r0 = xor32_sum(rp);                                                           \
    float z0 = xor32_sum(zp);                                                           \
    float in0 = xor32_sum(inp);                                                         \
    float hn0 = xor32_sum(hnp);                                                         \
    float r = sigmoid_f(r0), z = sigmoid_f(z0);                                         \
    float n = tanh_f(in0 + r * hn0);                                                    \
    h1 = n + z * (h1 - n);                                                              \
    if (hl == 0 && act) sh1[j] = h1;                                                    \
    __builtin_amdgcn_wave_barrier();                                                    \
    /* ---- deferred FC of step TT-1 (uses hv2h = h2_{TT-1}) ---- */                    \
    float op = fb_l;                                                                    \
    _Pragma("unroll")                                                                   \
    for (int i = 0; i < 6; ++i) op += hv2h[i] * fw6[i];                                 \
    float o = xor32_sum(op);                                                            \
    if (TT > 0 && hl == 0 && lane15 == 0) outp[TT - 1] = o;                             \
    /* ---- layer 1 hh partials (h2_{TT-1}, already in regs) ---- */                    \
    float r1p = rb1, z1p = zb1, hn1p = hnb1;                                            \
    _Pragma("unroll")                                                                   \
    for (int i = 0; i < 6; ++i) {                                                       \
      r1p += hv2h[i] * wr1h[i]; z1p += hv2h[i] * wz1h[i]; hn1p += hv2h[i] * wn1h[i];    \
    }                                                                                   \
    /* ---- read back h1_t (write had hh1+fc time to complete) ---- */                  \
    _Pragma("unroll")                                                                   \
    for (int i = 0; i < 6; ++i) hv1h[i] = sh1[hl * 6 + i];                              \
    float in1p = inb1;                                                                  \
    _Pragma("unroll")                                                                   \
    for (int i = 0; i < 6; ++i) {                                                       \
      r1p += hv1h[i] * wr1i[i]; z1p += hv1h[i] * wz1i[i]; in1p += hv1h[i] * wn1i[i];    \
    }                                                                                   \
    float r1t = xor32_sum(r1p);                                                         \
    float z1t = xor32_sum(z1p);                                                         \
    float in1 = xor32_sum(in1p);                                                        \
    float hn1 = xor32_sum(hn1p);                                                        \
    float r1 = sigmoid_f(r1t), z1 = sigmoid_f(z1t);                                     \
    float n1 = tanh_f(in1 + r1 * hn1);                                                  \
    h2 = n1 + z1 * (h2 - n1);                                                           \
    if (hl == 0 && act) sh2[j] = h2;                                                    \
    __builtin_amdgcn_wave_barrier();                                                    \
    /* ---- issue h2_t read now; consumed after next step's layer-0 ---- */             \
    _Pragma("unroll")                                                                   \
    for (int i = 0; i < 6; ++i) hv2h[i] = sh2[hl * 6 + i];                              \
  } while (0)

  for (int t = 0; t < Tlen; t += 2) {
    {  // prefetch x for t+1
      const float* p = xp + (size_t)(t + 1) * IND;
#pragma unroll
      for (int i = 0; i < 9; ++i) xB[i] = p[i];
    }
    STEP(xA, t);
    if (t + 2 < Tlen) {  // prefetch x for t+2
      const float* p = xp + (size_t)(t + 2) * IND;
#pragma unroll
      for (int i = 0; i < 9; ++i) xA[i] = p[i];
    }
    STEP(xB, t + 1);
  }
#undef STEP

  // epilogue: FC for t = Tlen-1 (hv2h = h2_{T-1})
  {
    float op = fb_l;
#pragma unroll
    for (int i = 0; i < 6; ++i) op += hv2h[i] * fw6[i];
    float o = xor32_sum(op);
    if (hl == 0 && lane15 == 0) outp[Tlen - 1] = o;
  }
}

extern "C" void kernel_launch(void* const* d_in, const int* in_sizes, int n_in,
                              void* d_out, int out_size, void* d_ws, size_t ws_size,
                              hipStream_t stream) {
  (void)in_sizes; (void)n_in; (void)d_ws; (void)ws_size; (void)out_size;
  const float* x    = (const float*)d_in[0];
  const float* wih0 = (const float*)d_in[1];
  const float* whh0 = (const float*)d_in[2];
  const float* bih0 = (const float*)d_in[3];
  const float* bhh0 = (const float*)d_in[4];
  const float* wih1 = (const float*)d_in[5];
  const float* whh1 = (const float*)d_in[6];
  const float* bih1 = (const float*)d_in[7];
  const float* bhh1 = (const float*)d_in[8];
  const float* fcw  = (const float*)d_in[9];
  const float* fcb  = (const float*)d_in[10];
  float* out = (float*)d_out;

  hipLaunchKernelGGL(gru2_pl32, dim3(Bsz / 8), dim3(256), 0, stream,
                     x, wih0, whh0, bih0, bhh0, wih1, whh1, bih1, bhh1, fcw, fcb, out);
}